// Round 2
// baseline (440.139 us; speedup 1.0000x reference)
//
#include <hip/hip_runtime.h>
#include <cstdint>
#include <math.h>

#define B_ 64
#define S_ 512
#define H_ 1024
#define T_ 24

// ---------------------------------------------------------------------------
// Kernel 1: emission[b,s,t] = sum_h feats[b,s,h]*W[t,h] + bias[t]
// grid 512 blocks x 256 thr. Each block: 64 rows. Wave w (0..3) computes
// t-slice [6w, 6w+6) for all 64 rows (lane = row). W reads are wave-uniform
// (t0 via readfirstlane) -> scalar loads. Feats staged coalesced into LDS.
// ---------------------------------------------------------------------------
__global__ __launch_bounds__(256) void gemm_kernel(const float* __restrict__ feats,
                                                   const float* __restrict__ W,
                                                   const float* __restrict__ bias,
                                                   float* __restrict__ emission) {
    __shared__ float tile[64 * 68];   // 64 rows x 64 floats, pad to 68 (16B-aligned rows)
    const int tid  = threadIdx.x;
    const int lane = tid & 63;
    const int t0   = __builtin_amdgcn_readfirstlane(tid >> 6) * 6;
    const long row0 = (long)blockIdx.x * 64;
    const float* fbase = feats + row0 * H_;

    float acc[6] = {0.f, 0.f, 0.f, 0.f, 0.f, 0.f};

    // register prefetch of chunk 0 (64 rows x 64 h = 1024 float4, 4 per thread)
    float4 pre[4];
#pragma unroll
    for (int i = 0; i < 4; ++i) {
        int f = i * 256 + tid;
        int r = f >> 4, c4 = f & 15;
        pre[i] = *(const float4*)(fbase + (long)r * H_ + c4 * 4);
    }

    for (int c = 0; c < 16; ++c) {
        const int hc = c * 64;
        __syncthreads();   // previous chunk's LDS reads done
#pragma unroll
        for (int i = 0; i < 4; ++i) {
            int f = i * 256 + tid;
            int r = f >> 4, c4 = f & 15;
            *(float4*)(&tile[r * 68 + c4 * 4]) = pre[i];
        }
        // issue next chunk's global loads; they fly during compute
        if (c + 1 < 16) {
#pragma unroll
            for (int i = 0; i < 4; ++i) {
                int f = i * 256 + tid;
                int r = f >> 4, c4 = f & 15;
                pre[i] = *(const float4*)(fbase + (long)r * H_ + (hc + 64) + c4 * 4);
            }
        }
        __syncthreads();   // tile visible

#pragma unroll
        for (int hh = 0; hh < 16; ++hh) {
            const float4 fv = *(const float4*)(&tile[lane * 68 + hh * 4]);
#pragma unroll
            for (int t = 0; t < 6; ++t) {
                const float4 wv = *(const float4*)(W + (long)(t0 + t) * H_ + hc + hh * 4);
                acc[t] = fmaf(fv.x, wv.x, acc[t]);
                acc[t] = fmaf(fv.y, wv.y, acc[t]);
                acc[t] = fmaf(fv.z, wv.z, acc[t]);
                acc[t] = fmaf(fv.w, wv.w, acc[t]);
            }
        }
    }

    const long row = row0 + lane;
    float* out = emission + row * T_ + t0;
#pragma unroll
    for (int t = 0; t < 6; ++t) out[t] = acc[t] + bias[t0 + t];
}

// ---------------------------------------------------------------------------
// Kernel 2: gold-path score per batch. One wave per batch.
// mask arrives as int32 (harness promotes bool -> int32).
// ---------------------------------------------------------------------------
__global__ __launch_bounds__(64) void score_kernel(const float* __restrict__ emission,
                                                   const int* __restrict__ target,
                                                   const int* __restrict__ mask,
                                                   const float* __restrict__ trans,
                                                   float* __restrict__ ws_score) {
    const int b = blockIdx.x;
    const int lane = threadIdx.x;
    float sum = 0.f;
    for (int s = lane; s < S_; s += 64) {
        if (mask[b * S_ + s]) {
            const int tg = target[b * S_ + s];
            float v = emission[((long)b * S_ + s) * T_ + tg];
            if (s > 0) v += trans[target[b * S_ + s - 1] * T_ + tg];
            sum += v;
        }
    }
#pragma unroll
    for (int off = 32; off; off >>= 1) sum += __shfl_down(sum, off);
    if (lane == 0) ws_score[b] = sum;
}

// ---------------------------------------------------------------------------
// Kernel 3: forward algorithm (log-partition) per batch. One wave per batch.
// Exp-domain: p = pr + C;  new_p[j] = C + log(sum_i exp(pr_i)*E[i][j]) + emit_j
// with E = exp(trans) precomputed; renormalize each step by lane-0's value.
// Emission loads software-pipelined 8 deep.
// ---------------------------------------------------------------------------
__global__ __launch_bounds__(64) void scan_kernel(const float* __restrict__ emission,
                                                  const int* __restrict__ mask,
                                                  const float* __restrict__ trans,
                                                  float* __restrict__ ws_logZ) {
    const int b = blockIdx.x;
    const int j = threadIdx.x;          // math lanes j<24; others are dummies
    const int jj = j < 24 ? j : 23;     // clamp to keep loads in-bounds
    __shared__ __align__(16) float qsh[32];

    const float* em = emission + (long)b * S_ * T_;
    const int* mk = mask + b * S_;

    float E[24];
#pragma unroll
    for (int i = 0; i < 24; ++i) E[i] = __expf(trans[i * T_ + jj]);

    float pr = (j < 24) ? em[j] : -INFINITY;
    float C = 0.f;

    // software-pipelined emission buffer, depth 8
    float ebuf[8];
#pragma unroll
    for (int k = 0; k < 8; ++k) ebuf[k] = em[(1 + k) * T_ + jj];

    for (int sb = 1; sb < S_; sb += 8) {
#pragma unroll
        for (int k = 0; k < 8; ++k) {
            const int s = sb + k;
            if (s < S_) {
                const float emit = ebuf[k];
                const int sp = s + 8;
                ebuf[k] = (sp < S_) ? em[sp * T_ + jj] : 0.f;

                if (mk[s]) {   // block-uniform branch (one batch per block)
                    const float q = __expf(pr);       // lanes>=24: exp(-inf)=0
                    if (j < 24) qsh[j] = q;
                    __syncthreads();
                    float s0 = 0.f, s1 = 0.f;
                    const float4* q4 = (const float4*)qsh;
#pragma unroll
                    for (int g = 0; g < 6; ++g) {
                        const float4 qv = q4[g];
                        float* dst = (g & 1) ? &s1 : &s0;
                        *dst = fmaf(qv.x, E[g * 4 + 0], *dst);
                        *dst = fmaf(qv.y, E[g * 4 + 1], *dst);
                        *dst = fmaf(qv.z, E[g * 4 + 2], *dst);
                        *dst = fmaf(qv.w, E[g * 4 + 3], *dst);
                    }
                    __syncthreads();   // qsh reusable next step
                    const float u = __logf(s0 + s1) + emit;
                    const float r0 = __uint_as_float(
                        __builtin_amdgcn_readfirstlane(__float_as_uint(u)));
                    pr = (j < 24) ? (u - r0) : -INFINITY;
                    C += r0;
                }
            }
        }
    }

    float ex = (j < 24) ? __expf(pr) : 0.f;
#pragma unroll
    for (int off = 32; off; off >>= 1) ex += __shfl_down(ex, off);
    if (j == 0) ws_logZ[b] = C + __logf(ex);
}

// ---------------------------------------------------------------------------
// Kernel 4: loss = -mean(score - logZ)
// ---------------------------------------------------------------------------
__global__ __launch_bounds__(64) void finalize_kernel(const float* __restrict__ ws_score,
                                                      const float* __restrict__ ws_logZ,
                                                      float* __restrict__ out) {
    const int l = threadIdx.x;
    float v = ws_score[l] - ws_logZ[l];
#pragma unroll
    for (int off = 32; off; off >>= 1) v += __shfl_down(v, off);
    if (l == 0) out[0] = -v * (1.0f / B_);
}

extern "C" void kernel_launch(void* const* d_in, const int* in_sizes, int n_in,
                              void* d_out, int out_size, void* d_ws, size_t ws_size,
                              hipStream_t stream) {
    const float* feats  = (const float*)d_in[0];
    const int*   target = (const int*)d_in[1];
    const int*   mask   = (const int*)d_in[2];
    const float* W      = (const float*)d_in[3];
    const float* bias   = (const float*)d_in[4];
    const float* trans  = (const float*)d_in[5];

    float* out = (float*)d_out;
    float* emission = out + 1;            // output 1, written in place
    float* ws_score = (float*)d_ws;       // 64 floats
    float* ws_logZ  = ws_score + 64;      // 64 floats

    gemm_kernel<<<512, 256, 0, stream>>>(feats, W, bias, emission);
    score_kernel<<<64, 64, 0, stream>>>(emission, target, mask, trans, ws_score);
    scan_kernel<<<64, 64, 0, stream>>>(emission, mask, trans, ws_logZ);
    finalize_kernel<<<1, 64, 0, stream>>>(ws_score, ws_logZ, out);
}

// Round 4
// 340.535 us; speedup vs baseline: 1.2925x; 1.2925x over previous
//
#include <hip/hip_runtime.h>
#include <cstdint>
#include <math.h>

#define B_ 64
#define S_ 512
#define H_ 1024
#define T_ 24

typedef unsigned int u32;
// async global->LDS DMA, 16B per lane. LDS dest = wave-uniform base + lane*16.
#define GLD_LDS16(g, l)                                                        \
    __builtin_amdgcn_global_load_lds(                                          \
        (const __attribute__((address_space(1))) u32*)(g),                     \
        (__attribute__((address_space(3))) u32*)(l), 16, 0, 0)

// ---------------------------------------------------------------------------
// Kernel 1: emission[b,s,t] = sum_h feats[b,s,h]*W[t,h] + bias[t]
// 512 blocks x 512 thr (8 waves). Block owns 64 rows; wave w computes
// t in [3w, 3w+3) for all 64 rows (lane = row -> W addrs wave-uniform ->
// scalar loads). feats staged via global_load_lds (16B), double-buffered.
// LDS layout float4-COLUMN-major tile4[c4][row]: DMA writes (base+lane*16)
// and ds_read_b128 reads (8-lane phases cover banks 0..31 once) are both
// conflict-free; row-major 256B stride would alias banks 8-way.
// ---------------------------------------------------------------------------
__global__ __launch_bounds__(512) void gemm_kernel(const float* __restrict__ feats,
                                                   const float* __restrict__ W,
                                                   const float* __restrict__ bias,
                                                   float* __restrict__ emission) {
    __shared__ float4 tile4[2][1024];   // 2 x 16KB chunk buffers (64 rows x 64 h)
    const int tid  = threadIdx.x;
    const int lane = tid & 63;                                   // = row in block
    const int w    = __builtin_amdgcn_readfirstlane(tid >> 6);   // wave 0..7
    const int t0   = w * 3;
    const long row0 = (long)blockIdx.x * 64;
    const float* fbase = feats + row0 * H_;

    // wave w stages float4-columns c4 = 2w, 2w+1 of each chunk:
    // lane l fetches feats[row0+l][hc + c4*4 .. +3] -> tile4[buf][c4*64 + l]
    const float* g0 = fbase + (long)lane * H_ + (2 * w) * 4;
    const float* g1 = g0 + 4;

#define STAGE(c, buf)                                                          \
    do {                                                                       \
        GLD_LDS16(g0 + (c) * 64, &tile4[(buf)][(2 * w) * 64]);                 \
        GLD_LDS16(g1 + (c) * 64, &tile4[(buf)][(2 * w + 1) * 64]);             \
    } while (0)

    float acc[3] = {0.f, 0.f, 0.f};
    STAGE(0, 0);

    for (int c = 0; c < 16; ++c) {
        __syncthreads();                 // vmcnt(0)+barrier: DMA for buf c&1 done
        if (c + 1 < 16) STAGE(c + 1, (c + 1) & 1);
        const float4* tb = tile4[c & 1];
        const float* wb = W + (long)t0 * H_ + c * 64;
#pragma unroll
        for (int i = 0; i < 16; ++i) {
            const float4 fv = tb[i * 64 + lane];
#pragma unroll
            for (int t = 0; t < 3; ++t) {
                const float4 wv = *(const float4*)(wb + (long)t * H_ + i * 4);
                acc[t] = fmaf(fv.x, wv.x, acc[t]);
                acc[t] = fmaf(fv.y, wv.y, acc[t]);
                acc[t] = fmaf(fv.z, wv.z, acc[t]);
                acc[t] = fmaf(fv.w, wv.w, acc[t]);
            }
        }
    }

    float* out = emission + (row0 + lane) * T_ + t0;
#pragma unroll
    for (int t = 0; t < 3; ++t) out[t] = acc[t] + bias[t0 + t];
#undef STAGE
}

// ---------------------------------------------------------------------------
// Kernel 2: gold-path score per batch. One wave per batch.
// ---------------------------------------------------------------------------
__global__ __launch_bounds__(64) void score_kernel(const float* __restrict__ emission,
                                                   const int* __restrict__ target,
                                                   const int* __restrict__ mask,
                                                   const float* __restrict__ trans,
                                                   float* __restrict__ ws_score) {
    const int b = blockIdx.x;
    const int lane = threadIdx.x;
    float sum = 0.f;
    for (int s = lane; s < S_; s += 64) {
        if (mask[b * S_ + s]) {
            const int tg = target[b * S_ + s];
            float v = emission[((long)b * S_ + s) * T_ + tg];
            if (s > 0) v += trans[target[b * S_ + s - 1] * T_ + tg];
            sum += v;
        }
    }
#pragma unroll
    for (int off = 32; off; off >>= 1) sum += __shfl_down(sum, off);
    if (lane == 0) ws_score[b] = sum;
}

// ---------------------------------------------------------------------------
// Kernel 3: forward algorithm. One wave per batch; NO LDS, NO barriers.
// Exp-domain; renormalize by the ACTUAL computed u at lane 0 each step
// (pr = u - readlane(u,0)) -> pr bounded by across-lane spread of u (~±4),
// zero drift. (R3's constant-renorm had +0.17/step Jensen drift -> exp
// overflow. Do NOT move the renorm off the critical path.)
// q_i broadcast via v_readlane; mask is a contiguous prefix -> single len.
// ---------------------------------------------------------------------------
#define RL(x, i) __uint_as_float(__builtin_amdgcn_readlane(__float_as_uint(x), (i)))

__global__ __launch_bounds__(64) void scan_kernel(const float* __restrict__ emission,
                                                  const int* __restrict__ mask,
                                                  const float* __restrict__ trans,
                                                  float* __restrict__ ws_logZ) {
    const int b = blockIdx.x;
    const int j = threadIdx.x;          // math lanes j<24; others dummies
    const int jj = j < 24 ? j : 23;

    const float* em = emission + (long)b * S_ * T_;
    const int* mk = mask + b * S_;

    // len = sum(mask row) (prefix-contiguous by construction)
    int mc = 0;
#pragma unroll
    for (int k = 0; k < 8; ++k) mc += mk[j + k * 64];
#pragma unroll
    for (int off = 32; off; off >>= 1) mc += __shfl_xor(mc, off);
    const int len = __builtin_amdgcn_readfirstlane(mc);

    float E[24];
#pragma unroll
    for (int i = 0; i < 24; ++i) E[i] = __expf(trans[i * T_ + jj]);

    float pr = (j < 24) ? em[j] : 0.f;
    float C = 0.f;

    // emission prefetch ring, depth 16
    float ebuf[16];
#pragma unroll
    for (int k = 0; k < 16; ++k) ebuf[k] = em[(1 + k) * T_ + jj];

    for (int sb = 1; sb < S_; sb += 16) {
#pragma unroll
        for (int k = 0; k < 16; ++k) {
            const int s = sb + k;
            const float emit = ebuf[k];
            const int sp = s + 16;
            ebuf[k] = (sp < S_) ? em[sp * T_ + jj] : 0.f;

            if (s < len) {              // uniform branch (len in SGPR)
                const float q = __expf(pr);
                float s0 = 0.f, s1 = 0.f, s2 = 0.f, s3 = 0.f;
#pragma unroll
                for (int i = 0; i < 24; i += 4) {
                    s0 = fmaf(RL(q, i + 0), E[i + 0], s0);
                    s1 = fmaf(RL(q, i + 1), E[i + 1], s1);
                    s2 = fmaf(RL(q, i + 2), E[i + 2], s2);
                    s3 = fmaf(RL(q, i + 3), E[i + 3], s3);
                }
                const float u = __logf((s0 + s1) + (s2 + s3)) + emit;
                const float r = RL(u, 0);   // actual computed value: tracks drift
                pr = u - r;
                C += r;
            }
        }
    }

    float ex = (j < 24) ? __expf(pr) : 0.f;
#pragma unroll
    for (int off = 32; off; off >>= 1) ex += __shfl_down(ex, off);
    if (j == 0) ws_logZ[b] = C + __logf(ex);
}

// ---------------------------------------------------------------------------
// Kernel 4: loss = -mean(score - logZ)
// ---------------------------------------------------------------------------
__global__ __launch_bounds__(64) void finalize_kernel(const float* __restrict__ ws_score,
                                                      const float* __restrict__ ws_logZ,
                                                      float* __restrict__ out) {
    const int l = threadIdx.x;
    float v = ws_score[l] - ws_logZ[l];
#pragma unroll
    for (int off = 32; off; off >>= 1) v += __shfl_down(v, off);
    if (l == 0) out[0] = -v * (1.0f / B_);
}

extern "C" void kernel_launch(void* const* d_in, const int* in_sizes, int n_in,
                              void* d_out, int out_size, void* d_ws, size_t ws_size,
                              hipStream_t stream) {
    const float* feats  = (const float*)d_in[0];
    const int*   target = (const int*)d_in[1];
    const int*   mask   = (const int*)d_in[2];
    const float* W      = (const float*)d_in[3];
    const float* bias   = (const float*)d_in[4];
    const float* trans  = (const float*)d_in[5];

    float* out = (float*)d_out;
    float* emission = out + 1;            // output 1, written in place
    float* ws_score = (float*)d_ws;       // 64 floats
    float* ws_logZ  = ws_score + 64;      // 64 floats

    gemm_kernel<<<512, 512, 0, stream>>>(feats, W, bias, emission);
    score_kernel<<<64, 64, 0, stream>>>(emission, target, mask, trans, ws_score);
    scan_kernel<<<64, 64, 0, stream>>>(emission, mask, trans, ws_logZ);
    finalize_kernel<<<1, 64, 0, stream>>>(ws_score, ws_logZ, out);
}